// Round 2
// baseline (2575.907 us; speedup 1.0000x reference)
//
#include <hip/hip_runtime.h>
#include <hip/hip_bf16.h>

// Problem constants
#define BATCH   64
#define SEQ     512
#define IN0     512
#define HID     128
#define G3      384   // 3*HID
#define NLAY    5

// ---------------------------------------------------------------------------
// gemm_gx: gx[M=32768][384] = A[M][K] @ W[384][K]^T + bias[384]   (all fp32)
// Tile 64(M) x 64(N), block 256 threads, 4x4 microtile, K-step 32.
// ---------------------------------------------------------------------------
__global__ __launch_bounds__(256) void gemm_gx(const float* __restrict__ A,
                                               const float* __restrict__ W,
                                               const float* __restrict__ bias,
                                               float* __restrict__ gx,
                                               int K)
{
    // LDS tiles stored transposed: [k][row] so inner-loop reads are float4
    __shared__ __align__(16) float As[32][68];  // row stride 68 floats = 272B (16B-aligned, odd*16 → conflict-free)
    __shared__ __align__(16) float Bs[32][68];

    const int row0 = blockIdx.x * 64;
    const int col0 = blockIdx.y * 64;
    const int tid  = threadIdx.x;
    const int tx   = tid & 15;   // N groups of 4
    const int ty   = tid >> 4;   // M groups of 4
    const int r    = tid >> 2;          // staging row/col index (0..63)
    const int kc   = (tid & 3) * 8;     // staging k offset (0,8,16,24)

    float acc[4][4] = {};

    for (int k0 = 0; k0 < K; k0 += 32) {
        // ---- stage A tile ----
        {
            const float* Ap = A + (size_t)(row0 + r) * K + k0 + kc;
            float4 a0 = *(const float4*)(Ap);
            float4 a1 = *(const float4*)(Ap + 4);
            As[kc + 0][r] = a0.x; As[kc + 1][r] = a0.y; As[kc + 2][r] = a0.z; As[kc + 3][r] = a0.w;
            As[kc + 4][r] = a1.x; As[kc + 5][r] = a1.y; As[kc + 6][r] = a1.z; As[kc + 7][r] = a1.w;
        }
        // ---- stage B tile (W rows = output cols) ----
        {
            const float* Wp = W + (size_t)(col0 + r) * K + k0 + kc;
            float4 b0 = *(const float4*)(Wp);
            float4 b1 = *(const float4*)(Wp + 4);
            Bs[kc + 0][r] = b0.x; Bs[kc + 1][r] = b0.y; Bs[kc + 2][r] = b0.z; Bs[kc + 3][r] = b0.w;
            Bs[kc + 4][r] = b1.x; Bs[kc + 5][r] = b1.y; Bs[kc + 6][r] = b1.z; Bs[kc + 7][r] = b1.w;
        }
        __syncthreads();

        #pragma unroll
        for (int kk = 0; kk < 32; kk++) {
            float4 a = *(const float4*)&As[kk][ty * 4];
            float4 b = *(const float4*)&Bs[kk][tx * 4];
            acc[0][0] = fmaf(a.x, b.x, acc[0][0]); acc[0][1] = fmaf(a.x, b.y, acc[0][1]);
            acc[0][2] = fmaf(a.x, b.z, acc[0][2]); acc[0][3] = fmaf(a.x, b.w, acc[0][3]);
            acc[1][0] = fmaf(a.y, b.x, acc[1][0]); acc[1][1] = fmaf(a.y, b.y, acc[1][1]);
            acc[1][2] = fmaf(a.y, b.z, acc[1][2]); acc[1][3] = fmaf(a.y, b.w, acc[1][3]);
            acc[2][0] = fmaf(a.z, b.x, acc[2][0]); acc[2][1] = fmaf(a.z, b.y, acc[2][1]);
            acc[2][2] = fmaf(a.z, b.z, acc[2][2]); acc[2][3] = fmaf(a.z, b.w, acc[2][3]);
            acc[3][0] = fmaf(a.w, b.x, acc[3][0]); acc[3][1] = fmaf(a.w, b.y, acc[3][1]);
            acc[3][2] = fmaf(a.w, b.z, acc[3][2]); acc[3][3] = fmaf(a.w, b.w, acc[3][3]);
        }
        __syncthreads();
    }

    // epilogue: add bias, store float4
    float bb[4];
    #pragma unroll
    for (int j = 0; j < 4; j++) bb[j] = bias[col0 + tx * 4 + j];
    #pragma unroll
    for (int i = 0; i < 4; i++) {
        const int row = row0 + ty * 4 + i;
        float4 v;
        v.x = acc[i][0] + bb[0];
        v.y = acc[i][1] + bb[1];
        v.z = acc[i][2] + bb[2];
        v.w = acc[i][3] + bb[3];
        *(float4*)&gx[(size_t)row * G3 + col0 + tx * 4] = v;
    }
}

// ---------------------------------------------------------------------------
// gru_scan: one block per batch element, 768 threads = 384 gate rows x 2 k-halves.
// Thread (g, half) holds w_hh[g][half*64 .. +64) in VGPRs (fp32).
// h state (128 fp32) + gate partials (768) + double-buffered gx stage in LDS.
// Two barriers per timestep.  gx prefetched one step ahead (HBM latency hide).
// ---------------------------------------------------------------------------
__global__ __launch_bounds__(768) void gru_scan(const float* __restrict__ gx,    // [BATCH][SEQ][384]
                                                const float* __restrict__ w_hh,  // [384][128] layer slice
                                                const float* __restrict__ b_hh,  // [384] layer slice
                                                float* __restrict__ hseq)        // [BATCH][SEQ][128]
{
    const int b    = blockIdx.x;
    const int tid  = threadIdx.x;
    const int g    = tid % 384;     // gate row (waves 0-5: half 0, waves 6-11: half 1 — wave-uniform)
    const int half = tid / 384;

    __shared__ __align__(16) float hs[HID];
    __shared__ float ghs[768];
    __shared__ float gxs[2][G3];

    // load this thread's 64 weights into VGPRs
    float w[64];
    {
        const float4* wp = (const float4*)(w_hh + (size_t)g * HID + half * 64); // 16B aligned
        #pragma unroll
        for (int q = 0; q < 16; q++) {
            float4 f = wp[q];
            w[q * 4 + 0] = f.x; w[q * 4 + 1] = f.y; w[q * 4 + 2] = f.z; w[q * 4 + 3] = f.w;
        }
    }
    const float bh = half ? 0.f : b_hh[g];

    if (tid < HID) hs[tid] = 0.f;
    const float* gxb = gx + (size_t)b * SEQ * G3;
    if (tid < G3) gxs[0][tid] = gxb[tid];
    __syncthreads();

    for (int t = 0; t < SEQ; t++) {
        // prefetch next timestep's gx (consumed next iteration)
        float nx = 0.f;
        if (tid < G3 && t + 1 < SEQ) nx = gxb[(size_t)(t + 1) * G3 + tid];

        // matvec half-row: 64 FMAs, 4 independent accumulators, LDS broadcast reads
        const float4* hv = (const float4*)(hs + half * 64);
        float a0 = 0.f, a1 = 0.f, a2 = 0.f, a3 = 0.f;
        #pragma unroll
        for (int kk = 0; kk < 16; kk++) {
            float4 h4 = hv[kk];
            a0 = fmaf(w[4 * kk + 0], h4.x, a0);
            a1 = fmaf(w[4 * kk + 1], h4.y, a1);
            a2 = fmaf(w[4 * kk + 2], h4.z, a2);
            a3 = fmaf(w[4 * kk + 3], h4.w, a3);
        }
        ghs[tid] = ((a0 + a1) + (a2 + a3)) + bh;
        if (tid < G3 && t + 1 < SEQ) gxs[(t + 1) & 1][tid] = nx;
        __syncthreads();

        if (tid < HID) {
            const int j = tid;
            const float* gc = gxs[t & 1];
            const float ghr = ghs[j]       + ghs[384 + j];
            const float ghz = ghs[128 + j] + ghs[512 + j];
            const float ghn = ghs[256 + j] + ghs[640 + j];
            const float rg = 1.f / (1.f + __expf(-(gc[j]       + ghr)));
            const float zg = 1.f / (1.f + __expf(-(gc[128 + j] + ghz)));
            const float ng = tanhf(gc[256 + j] + rg * ghn);
            const float hnew = fmaf(zg, hs[j] - ng, ng);   // (1-z)*n + z*h
            hs[j] = hnew;
            hseq[(size_t)b * (SEQ * HID) + (size_t)t * HID + j] = hnew;
        }
        __syncthreads();
    }
}

// ---------------------------------------------------------------------------
// fc: out[b][o] = hseq[b][T-1][:] . fc_w[o][:] + fc_b[o]   (fp32 out)
// ---------------------------------------------------------------------------
__global__ __launch_bounds__(128) void fc_kernel(const float* __restrict__ hseq,
                                                 const float* __restrict__ fc_w,
                                                 const float* __restrict__ fc_b,
                                                 float* __restrict__ out)
{
    const int b = blockIdx.x;
    const int o = threadIdx.x;
    if (o < 96) {
        const float* h = hseq + (size_t)b * (SEQ * HID) + (size_t)(SEQ - 1) * HID;
        const float* wrow = fc_w + o * HID;
        float acc = fc_b[o];
        #pragma unroll 4
        for (int k = 0; k < HID; k++) acc = fmaf(h[k], wrow[k], acc);
        out[b * 96 + o] = acc;
    }
}

// ---------------------------------------------------------------------------
extern "C" void kernel_launch(void* const* d_in, const int* in_sizes, int n_in,
                              void* d_out, int out_size, void* d_ws, size_t ws_size,
                              hipStream_t stream)
{
    const float* x         = (const float*)d_in[0]; // [64][512][512]
    const float* w_ih0     = (const float*)d_in[1]; // [384][512]
    const float* w_ih_rest = (const float*)d_in[2]; // [4][384][128]
    const float* w_hh      = (const float*)d_in[3]; // [5][384][128]
    const float* b_ih      = (const float*)d_in[4]; // [5][384]
    const float* b_hh      = (const float*)d_in[5]; // [5][384]
    const float* fc_w      = (const float*)d_in[6]; // [96][128]
    const float* fc_b      = (const float*)d_in[7]; // [96]
    float* out = (float*)d_out;                     // [64][96]

    // workspace: gx buffer (32768*384 fp32 = 50.3MB) + hseq (32768*128 fp32 = 16.8MB)
    float* gxbuf = (float*)d_ws;
    float* hseq  = gxbuf + (size_t)32768 * G3;

    const dim3 gemmGrid(512, 6);

    // layer 0
    gemm_gx<<<gemmGrid, 256, 0, stream>>>(x, w_ih0, b_ih, gxbuf, IN0);
    gru_scan<<<BATCH, 768, 0, stream>>>(gxbuf, w_hh, b_hh, hseq);

    // layers 1..4  (gemm for layer l reads hseq written by layer l-1; stream-ordered)
    for (int l = 1; l < NLAY; l++) {
        gemm_gx<<<gemmGrid, 256, 0, stream>>>(hseq,
                                              w_ih_rest + (size_t)(l - 1) * G3 * HID,
                                              b_ih + (size_t)l * G3,
                                              gxbuf, HID);
        gru_scan<<<BATCH, 768, 0, stream>>>(gxbuf,
                                            w_hh + (size_t)l * G3 * HID,
                                            b_hh + (size_t)l * G3,
                                            hseq);
    }

    fc_kernel<<<BATCH, 128, 0, stream>>>(hseq, fc_w, fc_b, out);
}